// Round 9
// baseline (110.313 us; speedup 1.0000x reference)
//
#include <hip/hip_runtime.h>

// Channel_mixing8 — R9 DIAGNOSTIC round.
// Exact R6 structure (best so far, ~32.6us est.) with the tile loop run
// npass=2 times (runtime arg; acc rezeroed per pass; output identical).
// Purpose: double the duration past the harness's 44us re-poison fills so
// the kernel's rocprof counters become visible for the first time since R3.
// VALUBusy >=80% -> issue-bound (then derive true cy/instr); <=50% ->
// latency-bound on exp/DPP/rcp chains. FETCH/WRITE verify memory model.

constexpr int C    = 64;
constexpr int HW   = 128 * 128;          // 16384 = 1<<14
constexpr int NPIX = 2 * HW;             // 32768
constexpr int JT   = 4;                  // j-tile
constexpr int PXB  = 32;                 // pixels per block
constexpr int LSTR = 68;                 // LDS row stride (floats); 272B, 16B-aligned
#define LOG2E 1.4426950408889634f

template <int CTRL>
__device__ __forceinline__ float dpp_add(float x) {
  int xi = __builtin_bit_cast(int, x);
  int yi = __builtin_amdgcn_update_dpp(0, xi, CTRL, 0xF, 0xF, true);
  return x + __builtin_bit_cast(float, yi);
}

__global__ __launch_bounds__(256, 4) void channel_mixing_kernel(
    const float* __restrict__ q,    // x
    const float* __restrict__ kk,   // y
    const float* __restrict__ v,    // z
    float* __restrict__ out,
    int npass) {
  __shared__ __align__(16) float lds_k[PXB * LSTR];
  __shared__ __align__(16) float lds_q[PXB * LSTR];

  const int t        = threadIdx.x;
  const int pixblock = blockIdx.x * PXB;
  // [b,c,h,w]: elem(b,c,phw) = (b<<20) + (c<<14) + phw; blocks never straddle b
  const int gbase = ((pixblock >> 14) << 20) | (pixblock & (HW - 1));

  const int lane = t & 63;
  const int p    = lane >> 3;                  // pixel-in-wave [0,8)
  const int ig   = lane & 7;                   // i-group [0,8): channels ig*8..+7
  const int px   = (t >> 6) * 8 + p;           // pixel-in-block [0,32)
  const int base  = gbase + px;
  const int cbase = base + (ig << 17);         // c = ig*8

  // my 8 v-channels (packed pairs), pre-scaled: arg = (v*log2e)*k
  float2 vv2[4];
#pragma unroll
  for (int n = 0; n < 4; ++n) {
    float a = v[cbase + ((2 * n) << 14)];
    float b = v[cbase + ((2 * n + 1) << 14)];
    vv2[n] = make_float2(a * LOG2E, b * LOG2E);
  }

  // ---- stage k,q: 64 j x 32 px, fully coalesced float4 loads along px ----
#pragma unroll
  for (int rep = 0; rep < 2; ++rep) {
    const int s  = rep * 256 + t;     // float4-slot [0,512)
    const int j  = s >> 3;            // [0,64)
    const int pg = (s & 7) * 4;       // px group start
    float4 k4 = *(const float4*)&kk[gbase + (j << 14) + pg];
    float4 q4 = *(const float4*)&q [gbase + (j << 14) + pg];
    lds_k[(pg + 0) * LSTR + j] = k4.x;  lds_q[(pg + 0) * LSTR + j] = q4.x;
    lds_k[(pg + 1) * LSTR + j] = k4.y;  lds_q[(pg + 1) * LSTR + j] = q4.y;
    lds_k[(pg + 2) * LSTR + j] = k4.z;  lds_q[(pg + 2) * LSTR + j] = q4.z;
    lds_k[(pg + 3) * LSTR + j] = k4.w;  lds_q[(pg + 3) * LSTR + j] = q4.w;
  }

  __syncthreads();

  const float4* lkp4 = (const float4*)&lds_k[px * LSTR];
  const float4* lqp4 = (const float4*)&lds_q[px * LSTR];

  float2 acc2[4];

  for (int pass = 0; pass < npass; ++pass) {
#pragma unroll
    for (int n = 0; n < 4; ++n) acc2[n] = make_float2(0.0f, 0.0f);

    float4 kx4 = lkp4[0];
    float4 qx4 = lqp4[0];

#pragma unroll 1
    for (int jt = 0; jt < C / JT; ++jt) {
      const int nxt = (jt < C / JT - 1) ? jt + 1 : jt;
      float4 kxn = lkp4[nxt];               // prefetch next tile
      float4 qxn = lqp4[nxt];

      const float kx[JT] = {kx4.x, kx4.y, kx4.z, kx4.w};
      const float qx[JT] = {qx4.x, qx4.y, qx4.z, qx4.w};

      // 32 exps per tile (trans pipe)
      float2 e2[JT][4];
#pragma unroll
      for (int jj = 0; jj < JT; ++jj)
#pragma unroll
        for (int n = 0; n < 4; ++n) {
          float mx = vv2[n].x * kx[jj];
          float my = vv2[n].y * kx[jj];
          e2[jj][n] = make_float2(__builtin_amdgcn_exp2f(mx),
                                  __builtin_amdgcn_exp2f(my));
        }

      // batched column sums: tree + 3-stage DPP over the 8-lane group
      float S[JT];
#pragma unroll
      for (int jj = 0; jj < JT; ++jj) {
        float2 a = make_float2(e2[jj][0].x + e2[jj][1].x, e2[jj][0].y + e2[jj][1].y);
        float2 b = make_float2(e2[jj][2].x + e2[jj][3].x, e2[jj][2].y + e2[jj][3].y);
        float2 c = make_float2(a.x + b.x, a.y + b.y);
        S[jj] = c.x + c.y;
      }
#pragma unroll
      for (int jj = 0; jj < JT; ++jj) S[jj] = dpp_add<0xB1>(S[jj]);   // xor1
#pragma unroll
      for (int jj = 0; jj < JT; ++jj) S[jj] = dpp_add<0x4E>(S[jj]);   // xor2
#pragma unroll
      for (int jj = 0; jj < JT; ++jj) S[jj] = dpp_add<0x141>(S[jj]);  // i^7

#pragma unroll
      for (int jj = 0; jj < JT; ++jj) {
        const float w = qx[jj] * __builtin_amdgcn_rcpf(S[jj]);
#pragma unroll
        for (int n = 0; n < 4; ++n) {
          acc2[n].x += w * e2[jj][n].x;
          acc2[n].y += w * e2[jj][n].y;
        }
      }

      kx4 = kxn;
      qx4 = qxn;
    }
  }

#pragma unroll
  for (int n = 0; n < 4; ++n) {
    out[cbase + ((2 * n) << 14)]     = acc2[n].x;
    out[cbase + ((2 * n + 1) << 14)] = acc2[n].y;
  }
}

extern "C" void kernel_launch(void* const* d_in, const int* in_sizes, int n_in,
                              void* d_out, int out_size, void* d_ws, size_t ws_size,
                              hipStream_t stream) {
  const float* q  = (const float*)d_in[0];  // x
  const float* kk = (const float*)d_in[1];  // y
  const float* v  = (const float*)d_in[2];  // z
  float* out = (float*)d_out;

  dim3 grid(NPIX / PXB);   // 1024 blocks x 256 threads, 32 px per block
  dim3 block(256);
  // npass=2: diagnostic doubling to surface rocprof counters (same output)
  channel_mixing_kernel<<<grid, block, 0, stream>>>(q, kk, v, out, 2);
}

// Round 10
// 98.538 us; speedup vs baseline: 1.1195x; 1.1195x over previous
//
#include <hip/hip_runtime.h>

// Channel_mixing8: per-pixel (B*H*W = 32768) over C=64 channels:
//   attn[i,j] = softmax_i( v[i]*k[j] );  out[i] = sum_j attn[i,j] * q[j]
// Restructured: S_j = sum_i exp(v_i k_j);  out_i = sum_j (q_j / S_j) * exp(v_i k_j)
//
// R10: R9 diagnostic showed VALUBusy=65% at 4 waves/SIMD (grid-fixed), HBM 5%,
// conflicts negligible -> ~35% dependency stall in the per-tile reduce chain
// (tree -> 3xDPP -> rcp -> fma). Fix: 2-deep software pipeline across j-tiles
// (eA/eB rotation): tile t+1's 32 independent v_exp issue while tile t's
// serial reduce chain drains. ~110 VGPR, still 4 waves/SIMD at 128 cap.

constexpr int C    = 64;
constexpr int HW   = 128 * 128;          // 16384 = 1<<14
constexpr int NPIX = 2 * HW;             // 32768
constexpr int JT   = 4;                  // j-tile
constexpr int NT   = C / JT;             // 16 tiles
constexpr int PXB  = 32;                 // pixels per block
constexpr int LSTR = 68;                 // LDS row stride (floats); 272B, 16B-aligned
#define LOG2E 1.4426950408889634f

template <int CTRL>
__device__ __forceinline__ float dpp_add(float x) {
  int xi = __builtin_bit_cast(int, x);
  int yi = __builtin_amdgcn_update_dpp(0, xi, CTRL, 0xF, 0xF, true);
  return x + __builtin_bit_cast(float, yi);
}

__device__ __forceinline__ void tile_exps(float2 e2[JT][4], const float2 vv2[4],
                                          const float4& kx4) {
  const float kx[JT] = {kx4.x, kx4.y, kx4.z, kx4.w};
#pragma unroll
  for (int jj = 0; jj < JT; ++jj)
#pragma unroll
    for (int n = 0; n < 4; ++n) {
      float mx = vv2[n].x * kx[jj];
      float my = vv2[n].y * kx[jj];
      e2[jj][n] = make_float2(__builtin_amdgcn_exp2f(mx),
                              __builtin_amdgcn_exp2f(my));
    }
}

__device__ __forceinline__ void tile_reduce(const float2 e2[JT][4],
                                            const float4& qx4, float2 acc2[4]) {
  const float qx[JT] = {qx4.x, qx4.y, qx4.z, qx4.w};
  float S[JT];
#pragma unroll
  for (int jj = 0; jj < JT; ++jj) {
    float2 a = make_float2(e2[jj][0].x + e2[jj][1].x, e2[jj][0].y + e2[jj][1].y);
    float2 b = make_float2(e2[jj][2].x + e2[jj][3].x, e2[jj][2].y + e2[jj][3].y);
    float2 c = make_float2(a.x + b.x, a.y + b.y);
    S[jj] = c.x + c.y;
  }
#pragma unroll
  for (int jj = 0; jj < JT; ++jj) S[jj] = dpp_add<0xB1>(S[jj]);   // xor1
#pragma unroll
  for (int jj = 0; jj < JT; ++jj) S[jj] = dpp_add<0x4E>(S[jj]);   // xor2
#pragma unroll
  for (int jj = 0; jj < JT; ++jj) S[jj] = dpp_add<0x141>(S[jj]);  // i^7
#pragma unroll
  for (int jj = 0; jj < JT; ++jj) {
    const float w = qx[jj] * __builtin_amdgcn_rcpf(S[jj]);
#pragma unroll
    for (int n = 0; n < 4; ++n) {
      acc2[n].x += w * e2[jj][n].x;
      acc2[n].y += w * e2[jj][n].y;
    }
  }
}

__global__ __launch_bounds__(256, 4) void channel_mixing_kernel(
    const float* __restrict__ q,    // x
    const float* __restrict__ kk,   // y
    const float* __restrict__ v,    // z
    float* __restrict__ out) {
  __shared__ __align__(16) float lds_k[PXB * LSTR];
  __shared__ __align__(16) float lds_q[PXB * LSTR];

  const int t        = threadIdx.x;
  const int pixblock = blockIdx.x * PXB;
  // [b,c,h,w]: elem(b,c,phw) = (b<<20) + (c<<14) + phw; blocks never straddle b
  const int gbase = ((pixblock >> 14) << 20) | (pixblock & (HW - 1));

  const int lane = t & 63;
  const int p    = lane >> 3;                  // pixel-in-wave [0,8)
  const int ig   = lane & 7;                   // i-group [0,8): channels ig*8..+7
  const int px   = (t >> 6) * 8 + p;           // pixel-in-block [0,32)
  const int base  = gbase + px;
  const int cbase = base + (ig << 17);         // c = ig*8

  // my 8 v-channels (packed pairs), pre-scaled: arg = (v*log2e)*k
  float2 vv2[4];
#pragma unroll
  for (int n = 0; n < 4; ++n) {
    float a = v[cbase + ((2 * n) << 14)];
    float b = v[cbase + ((2 * n + 1) << 14)];
    vv2[n] = make_float2(a * LOG2E, b * LOG2E);
  }

  // ---- stage k,q: 64 j x 32 px, fully coalesced float4 loads along px ----
#pragma unroll
  for (int rep = 0; rep < 2; ++rep) {
    const int s  = rep * 256 + t;     // float4-slot [0,512)
    const int j  = s >> 3;            // [0,64)
    const int pg = (s & 7) * 4;       // px group start
    float4 k4 = *(const float4*)&kk[gbase + (j << 14) + pg];
    float4 q4 = *(const float4*)&q [gbase + (j << 14) + pg];
    lds_k[(pg + 0) * LSTR + j] = k4.x;  lds_q[(pg + 0) * LSTR + j] = q4.x;
    lds_k[(pg + 1) * LSTR + j] = k4.y;  lds_q[(pg + 1) * LSTR + j] = q4.y;
    lds_k[(pg + 2) * LSTR + j] = k4.z;  lds_q[(pg + 2) * LSTR + j] = q4.z;
    lds_k[(pg + 3) * LSTR + j] = k4.w;  lds_q[(pg + 3) * LSTR + j] = q4.w;
  }

  float2 acc2[4];
#pragma unroll
  for (int n = 0; n < 4; ++n) acc2[n] = make_float2(0.0f, 0.0f);

  __syncthreads();

  const float4* lkp4 = (const float4*)&lds_k[px * LSTR];
  const float4* lqp4 = (const float4*)&lds_q[px * LSTR];

  // ---- 2-deep software pipeline over 16 tiles (eA/eB rotation) ----
  float2 eA[JT][4], eB[JT][4];
  float4 kxA = lkp4[0], qxA = lqp4[0];
  tile_exps(eA, vv2, kxA);

#pragma unroll 1
  for (int jt = 0; jt < NT; jt += 2) {
    float4 kxB = lkp4[jt + 1], qxB = lqp4[jt + 1];
    tile_exps(eB, vv2, kxB);            // tile jt+1 exps issue...
    tile_reduce(eA, qxA, acc2);         // ...while tile jt's chain drains
    if (jt + 2 < NT) {
      kxA = lkp4[jt + 2]; qxA = lqp4[jt + 2];
      tile_exps(eA, vv2, kxA);          // tile jt+2 exps...
    }
    tile_reduce(eB, qxB, acc2);         // ...while tile jt+1's chain drains
  }

#pragma unroll
  for (int n = 0; n < 4; ++n) {
    out[cbase + ((2 * n) << 14)]     = acc2[n].x;
    out[cbase + ((2 * n + 1) << 14)] = acc2[n].y;
  }
}

extern "C" void kernel_launch(void* const* d_in, const int* in_sizes, int n_in,
                              void* d_out, int out_size, void* d_ws, size_t ws_size,
                              hipStream_t stream) {
  const float* q  = (const float*)d_in[0];  // x
  const float* kk = (const float*)d_in[1];  // y
  const float* v  = (const float*)d_in[2];  // z
  float* out = (float*)d_out;

  dim3 grid(NPIX / PXB);   // 1024 blocks x 256 threads, 32 px per block
  dim3 block(256);
  channel_mixing_kernel<<<grid, block, 0, stream>>>(q, kk, v, out);
}

// Round 11
// 94.114 us; speedup vs baseline: 1.1721x; 1.0470x over previous
//
#include <hip/hip_runtime.h>

// Channel_mixing8: per-pixel (B*H*W = 32768) over C=64 channels:
//   attn[i,j] = softmax_i( v[i]*k[j] );  out[i] = sum_j attn[i,j] * q[j]
// Restructured: S_j = sum_i exp(v_i k_j);  out_i = sum_j (q_j / S_j) * exp(v_i k_j)
//
// R11: R9 counters -> v_exp ~12.6cy busy, 35% dependency idle at 4 waves/SIMD.
// R10 (pipeline via big e-buffers) regressed: register spills under 128-cap.
// Buy ILP with WAVES not registers: ICH=4 (16 lanes/px, 4-stage DPP, verified
// R5) + R6's float2 packing + JT=4, ~45 live VGPRs -> launch_bounds(256,8)
// 64-reg cap -> 8 waves/SIMD (2x R6). No prefetch rotation (TLP covers LDS).

constexpr int C    = 64;
constexpr int HW   = 128 * 128;          // 16384 = 1<<14
constexpr int NPIX = 2 * HW;             // 32768
constexpr int JT   = 4;                  // j-tile
constexpr int NT   = C / JT;             // 16 tiles
constexpr int PXB  = 16;                 // pixels per block (256 thr / 16 lanes)
constexpr int LSTR = 68;                 // LDS row stride (floats); 272B, 16B-aligned
#define LOG2E 1.4426950408889634f

template <int CTRL>
__device__ __forceinline__ float dpp_add(float x) {
  int xi = __builtin_bit_cast(int, x);
  int yi = __builtin_amdgcn_update_dpp(0, xi, CTRL, 0xF, 0xF, true);
  return x + __builtin_bit_cast(float, yi);
}

__global__ __launch_bounds__(256, 8) void channel_mixing_kernel(
    const float* __restrict__ q,    // x
    const float* __restrict__ kk,   // y
    const float* __restrict__ v,    // z
    float* __restrict__ out) {
  __shared__ __align__(16) float lds_k[PXB * LSTR];
  __shared__ __align__(16) float lds_q[PXB * LSTR];

  const int t        = threadIdx.x;
  const int pixblock = blockIdx.x * PXB;
  // [b,c,h,w]: elem(b,c,phw) = (b<<20) + (c<<14) + phw; blocks never straddle b
  const int gbase = ((pixblock >> 14) << 20) | (pixblock & (HW - 1));

  const int lane = t & 63;
  const int p    = lane >> 4;                  // pixel-in-wave [0,4)
  const int ig   = lane & 15;                  // i-group [0,16): channels ig*4..+3
  const int px   = (t >> 6) * 4 + p;           // pixel-in-block [0,16)
  const int base  = gbase + px;
  const int cbase = base + (ig << 16);         // c = ig*4

  // my 4 v-channels (2 packed pairs), pre-scaled: arg = (v*log2e)*k
  float2 vv2[2];
#pragma unroll
  for (int n = 0; n < 2; ++n) {
    float a = v[cbase + ((2 * n) << 14)];
    float b = v[cbase + ((2 * n + 1) << 14)];
    vv2[n] = make_float2(a * LOG2E, b * LOG2E);
  }

  // ---- stage k,q: 64 j x 16 px, fully coalesced float4 loads along px ----
  {
    const int j  = t >> 2;            // [0,64)
    const int pg = (t & 3) * 4;       // px group start [0,16)
    float4 k4 = *(const float4*)&kk[gbase + (j << 14) + pg];
    float4 q4 = *(const float4*)&q [gbase + (j << 14) + pg];
    lds_k[(pg + 0) * LSTR + j] = k4.x;  lds_q[(pg + 0) * LSTR + j] = q4.x;
    lds_k[(pg + 1) * LSTR + j] = k4.y;  lds_q[(pg + 1) * LSTR + j] = q4.y;
    lds_k[(pg + 2) * LSTR + j] = k4.z;  lds_q[(pg + 2) * LSTR + j] = q4.z;
    lds_k[(pg + 3) * LSTR + j] = k4.w;  lds_q[(pg + 3) * LSTR + j] = q4.w;
  }

  float2 acc2[2];
#pragma unroll
  for (int n = 0; n < 2; ++n) acc2[n] = make_float2(0.0f, 0.0f);

  __syncthreads();

  const float4* lkp4 = (const float4*)&lds_k[px * LSTR];
  const float4* lqp4 = (const float4*)&lds_q[px * LSTR];

#pragma unroll 1
  for (int jt = 0; jt < NT; ++jt) {
    float4 kx4 = lkp4[jt];                       // ds_read_b128
    float4 qx4 = lqp4[jt];
    const float kx[JT] = {kx4.x, kx4.y, kx4.z, kx4.w};
    const float qx[JT] = {qx4.x, qx4.y, qx4.z, qx4.w};

    // 16 exps per tile (trans), muls packed
    float2 e2[JT][2];
#pragma unroll
    for (int jj = 0; jj < JT; ++jj)
#pragma unroll
      for (int n = 0; n < 2; ++n) {
        float mx = vv2[n].x * kx[jj];
        float my = vv2[n].y * kx[jj];
        e2[jj][n] = make_float2(__builtin_amdgcn_exp2f(mx),
                                __builtin_amdgcn_exp2f(my));
      }

    // batched column sums: packed pair-add + 4-stage DPP over 16-lane group
    float S[JT];
#pragma unroll
    for (int jj = 0; jj < JT; ++jj) {
      float2 a = make_float2(e2[jj][0].x + e2[jj][1].x,
                             e2[jj][0].y + e2[jj][1].y);
      S[jj] = a.x + a.y;
    }
#pragma unroll
    for (int jj = 0; jj < JT; ++jj) S[jj] = dpp_add<0xB1>(S[jj]);   // xor1
#pragma unroll
    for (int jj = 0; jj < JT; ++jj) S[jj] = dpp_add<0x4E>(S[jj]);   // xor2
#pragma unroll
    for (int jj = 0; jj < JT; ++jj) S[jj] = dpp_add<0x141>(S[jj]);  // i^7 (half-mirror)
#pragma unroll
    for (int jj = 0; jj < JT; ++jj) S[jj] = dpp_add<0x140>(S[jj]);  // i^15 (mirror)

#pragma unroll
    for (int jj = 0; jj < JT; ++jj) {
      const float w = qx[jj] * __builtin_amdgcn_rcpf(S[jj]);
#pragma unroll
      for (int n = 0; n < 2; ++n) {                // v_pk_fma
        acc2[n].x += w * e2[jj][n].x;
        acc2[n].y += w * e2[jj][n].y;
      }
    }
  }

#pragma unroll
  for (int n = 0; n < 2; ++n) {
    out[cbase + ((2 * n) << 14)]     = acc2[n].x;
    out[cbase + ((2 * n + 1) << 14)] = acc2[n].y;
  }
}

extern "C" void kernel_launch(void* const* d_in, const int* in_sizes, int n_in,
                              void* d_out, int out_size, void* d_ws, size_t ws_size,
                              hipStream_t stream) {
  const float* q  = (const float*)d_in[0];  // x
  const float* kk = (const float*)d_in[1];  // y
  const float* v  = (const float*)d_in[2];  // z
  float* out = (float*)d_out;

  dim3 grid(NPIX / PXB);   // 2048 blocks x 256 threads, 16 px per block
  dim3 block(256);
  channel_mixing_kernel<<<grid, block, 0, stream>>>(q, kk, v, out);
}